// Round 1
// baseline (395.520 us; speedup 1.0000x reference)
//
#include <hip/hip_runtime.h>
#include <math.h>

// QGRUCell fused kernel — Round 1: correct fp32 baseline.
// gi = x @ Wih^T + bih ; gh = h @ Whh^T + bhh ; quantized GRU gate math fused
// into the GEMM epilogue. fp32 vector-ALU GEMM (no fp32 MFMA on CDNA4);
// later rounds will move to split-bf16 MFMA.

namespace {

constexpr int Bsz = 8192;   // batch
constexpr int Ksz = 512;    // input/hidden feature dim (I == H)
constexpr int Hsz = 512;    // hidden dim
constexpr int BM  = 64;     // block tile: batch rows
constexpr int BN  = 64;     // block tile: hidden cols
constexpr int KT  = 16;     // K tile
constexpr int LDP = BM + 4; // padded LDS leading dim ([k][m] layout)

__device__ __forceinline__ float qround(float x, float s, float invs) {
    // QuantMode.floor_add forward: floor(x*s + 0.5)/s  (fp32, matching jnp)
    return floorf(x * s + 0.5f) * invs;
}

// qsigmoid: Q27 input quant -> sigmoid -> Q31 -> requant Q15
__device__ __forceinline__ float qsigmoid_dev(float x) {
    float iq = floorf(x * 134217728.0f + 0.5f);              // * 2^27
    iq = fminf(fmaxf(iq, -2147483648.0f), 2147483648.0f);    // fp32(INT32_MAX)=2^31
    float s  = 1.0f / (1.0f + expf(-iq * 7.450580596923828125e-9f)); // iq / 2^27
    float q31 = floorf(s * 2147483648.0f + 0.5f);
    float q15 = floorf(q31 * 1.52587890625e-5f + 0.5f);      // * 2^-16
    return q15 * 3.0517578125e-5f;                           // / 2^15
}

__device__ __forceinline__ float qtanh_dev(float x) {
    float iq = floorf(x * 134217728.0f + 0.5f);
    iq = fminf(fmaxf(iq, -2147483648.0f), 2147483648.0f);
    float tv = tanhf(iq * 7.450580596923828125e-9f);
    float q31 = floorf(tv * 2147483648.0f + 0.5f);
    float q15 = floorf(q31 * 1.52587890625e-5f + 0.5f);
    return q15 * 3.0517578125e-5f;
}

} // namespace

__global__ __launch_bounds__(256, 2) void qgru_fused_f32(
    const float* __restrict__ x, const float* __restrict__ hid,
    const float* __restrict__ wih, const float* __restrict__ whh,
    const float* __restrict__ bih, const float* __restrict__ bhh,
    float* __restrict__ out)
{
    __shared__ float As[2][KT][LDP];   // [0]=x tile, [1]=hidden tile, [k][m]
    __shared__ float Ws[6][KT][LDP];   // gates r/i/n of Wih then Whh, [k][n]

    const int t    = threadIdx.x;
    const int m0   = blockIdx.x * BM;
    const int n0   = blockIdx.y * BN;
    const int lrow = t >> 2;           // 0..63   staging row
    const int lkq  = (t & 3) * 4;      // 0,4,8,12 staging k-quad
    const int tm   = (t >> 4) * 4;     // 0..60   compute row base (4 rows)
    const int tn   = (t & 15) * 4;     // 0..60   compute col base (4 cols)

    float acc[6][4][4];
#pragma unroll
    for (int g = 0; g < 6; ++g)
#pragma unroll
        for (int i = 0; i < 4; ++i)
#pragma unroll
            for (int j = 0; j < 4; ++j) acc[g][i][j] = 0.0f;

    const float* g_src[8];
    g_src[0] = x   + (size_t)(m0 + lrow) * Ksz + lkq;
    g_src[1] = hid + (size_t)(m0 + lrow) * Ksz + lkq;
    g_src[2] = wih + (size_t)(0 * Hsz + n0 + lrow) * Ksz + lkq;
    g_src[3] = wih + (size_t)(1 * Hsz + n0 + lrow) * Ksz + lkq;
    g_src[4] = wih + (size_t)(2 * Hsz + n0 + lrow) * Ksz + lkq;
    g_src[5] = whh + (size_t)(0 * Hsz + n0 + lrow) * Ksz + lkq;
    g_src[6] = whh + (size_t)(1 * Hsz + n0 + lrow) * Ksz + lkq;
    g_src[7] = whh + (size_t)(2 * Hsz + n0 + lrow) * Ksz + lkq;

    float* lds_dst[8];
    lds_dst[0] = &As[0][0][0];
    lds_dst[1] = &As[1][0][0];
#pragma unroll
    for (int g = 0; g < 6; ++g) lds_dst[2 + g] = &Ws[g][0][0];

    for (int k0 = 0; k0 < Ksz; k0 += KT) {
        float4 v[8];
#pragma unroll
        for (int p = 0; p < 8; ++p)
            v[p] = *(const float4*)(g_src[p] + k0);
        __syncthreads();   // previous iter's LDS reads done before overwrite
#pragma unroll
        for (int p = 0; p < 8; ++p) {
            float* d = lds_dst[p];
            d[(lkq + 0) * LDP + lrow] = v[p].x;
            d[(lkq + 1) * LDP + lrow] = v[p].y;
            d[(lkq + 2) * LDP + lrow] = v[p].z;
            d[(lkq + 3) * LDP + lrow] = v[p].w;
        }
        __syncthreads();

#pragma unroll
        for (int k = 0; k < KT; ++k) {
            float4 a4 = *(const float4*)&As[0][k][tm];
            float4 h4 = *(const float4*)&As[1][k][tm];
            float av[4] = {a4.x, a4.y, a4.z, a4.w};
            float hv[4] = {h4.x, h4.y, h4.z, h4.w};
            float wv[6][4];
#pragma unroll
            for (int g = 0; g < 6; ++g) {
                float4 w4 = *(const float4*)&Ws[g][k][tn];
                wv[g][0] = w4.x; wv[g][1] = w4.y; wv[g][2] = w4.z; wv[g][3] = w4.w;
            }
#pragma unroll
            for (int i = 0; i < 4; ++i) {
#pragma unroll
                for (int j = 0; j < 4; ++j) {
                    acc[0][i][j] = fmaf(av[i], wv[0][j], acc[0][i][j]);
                    acc[1][i][j] = fmaf(av[i], wv[1][j], acc[1][i][j]);
                    acc[2][i][j] = fmaf(av[i], wv[2][j], acc[2][i][j]);
                    acc[3][i][j] = fmaf(hv[i], wv[3][j], acc[3][i][j]);
                    acc[4][i][j] = fmaf(hv[i], wv[4][j], acc[4][i][j]);
                    acc[5][i][j] = fmaf(hv[i], wv[5][j], acc[5][i][j]);
                }
            }
        }
    }

    // ---- epilogue: quantized GRU gate chain ----
    constexpr float S14 = 16384.0f,     I14 = 1.0f / 16384.0f;
    constexpr float S15 = 32768.0f,     I15 = 1.0f / 32768.0f;
    constexpr float S27 = 134217728.0f, I27 = 1.0f / 134217728.0f;

    float b_r[4], b_i[4], b_n[4], c_r[4], c_i[4], c_n[4];
#pragma unroll
    for (int j = 0; j < 4; ++j) {
        int n = n0 + tn + j;
        b_r[j] = bih[n];  b_i[j] = bih[n + 512];  b_n[j] = bih[n + 1024];
        c_r[j] = bhh[n];  c_i[j] = bhh[n + 512];  c_n[j] = bhh[n + 1024];
    }

#pragma unroll
    for (int i = 0; i < 4; ++i) {
        const int m = m0 + tm + i;
        const float4 hv4 = *(const float4*)(hid + (size_t)m * Hsz + n0 + tn);
        const float hvv[4] = {hv4.x, hv4.y, hv4.z, hv4.w};
        float res[4];
#pragma unroll
        for (int j = 0; j < 4; ++j) {
            float gir = qround(acc[0][i][j] + b_r[j], S14, I14);
            float gii = qround(acc[1][i][j] + b_i[j], S14, I14);
            float gin = qround(acc[2][i][j] + b_n[j], S14, I14);
            float ghr = qround(acc[3][i][j] + c_r[j], S14, I14);
            float ghi = qround(acc[4][i][j] + c_i[j], S14, I14);
            float ghn = qround(acc[5][i][j] + c_n[j], S14, I14);
            float resetg = qsigmoid_dev(gir + ghr);
            float inputg = qsigmoid_dev(gii + ghi);
            float hn  = qround(ghn, S27, I27);           // Q27 requant (near no-op)
            float rh  = qround(resetg * hn, S15, I15);   // Q15 requant of r*h_n
            float newg = qtanh_dev(rh + gin);
            float nh  = qround(hvv[j], S15, I15);        // hidden requant Q15
            res[j] = newg + inputg * (nh - newg);
        }
        *(float4*)(out + (size_t)m * Hsz + n0 + tn) =
            make_float4(res[0], res[1], res[2], res[3]);
    }
}

extern "C" void kernel_launch(void* const* d_in, const int* in_sizes, int n_in,
                              void* d_out, int out_size, void* d_ws, size_t ws_size,
                              hipStream_t stream) {
    const float* x   = (const float*)d_in[0];
    const float* hid = (const float*)d_in[1];
    const float* wih = (const float*)d_in[2];
    const float* whh = (const float*)d_in[3];
    const float* bih = (const float*)d_in[4];
    const float* bhh = (const float*)d_in[5];
    float* out = (float*)d_out;

    dim3 grid(Bsz / BM, Hsz / BN);   // (128, 8): x-major so consecutive blocks
                                     // share the same weight tile (L2 locality)
    qgru_fused_f32<<<grid, dim3(256), 0, stream>>>(x, hid, wih, whh, bih, bhh, out);
}

// Round 3
// 220.638 us; speedup vs baseline: 1.7926x; 1.7926x over previous
//
#include <hip/hip_runtime.h>
#include <math.h>

// QGRUCell — Round 3: bf16x3 split MFMA GEMM + fused quantized gate epilogue.
// Identical to round 2 except the next-slab prefetch OOB bug is fixed
// (was gA+2*kn due to a leftover expression; faulted on the last rows).

typedef __bf16 bf16x8 __attribute__((ext_vector_type(8)));
typedef float  f32x16 __attribute__((ext_vector_type(16)));

namespace {

constexpr int Bsz = 8192;
constexpr int Ksz = 512;
constexpr int Hsz = 512;
constexpr int BM  = 64;
constexpr int BN  = 64;
constexpr int KT  = 16;

__device__ __forceinline__ float qround(float x, float s, float invs) {
    return floorf(x * s + 0.5f) * invs;
}

__device__ __forceinline__ float qsigmoid_dev(float x) {
    float iq = floorf(x * 134217728.0f + 0.5f);
    iq = fminf(fmaxf(iq, -2147483648.0f), 2147483648.0f);
    float s  = 1.0f / (1.0f + expf(-iq * 7.450580596923828125e-9f));
    float q31 = floorf(s * 2147483648.0f + 0.5f);
    float q15 = floorf(q31 * 1.52587890625e-5f + 0.5f);
    return q15 * 3.0517578125e-5f;
}

__device__ __forceinline__ float qtanh_dev(float x) {
    float iq = floorf(x * 134217728.0f + 0.5f);
    iq = fminf(fmaxf(iq, -2147483648.0f), 2147483648.0f);
    float tv = tanhf(iq * 7.450580596923828125e-9f);
    float q31 = floorf(tv * 2147483648.0f + 0.5f);
    float q15 = floorf(q31 * 1.52587890625e-5f + 0.5f);
    return q15 * 3.0517578125e-5f;
}

// Split (a,b) into packed bf16 hi pair and lo pair (RNE). hi = bf16(x),
// lo = bf16(x - f32(hi)); x - f32(hi) is exact in fp32.
__device__ __forceinline__ void split2(float a, float b, unsigned& hi, unsigned& lo) {
    unsigned ua = __float_as_uint(a); ua += 0x7fffu + ((ua >> 16) & 1u);
    unsigned ub = __float_as_uint(b); ub += 0x7fffu + ((ub >> 16) & 1u);
    hi = (ua >> 16) | (ub & 0xffff0000u);
    float ra = a - __uint_as_float(ua & 0xffff0000u);
    float rb = b - __uint_as_float(ub & 0xffff0000u);
    unsigned va = __float_as_uint(ra); va += 0x7fffu + ((va >> 16) & 1u);
    unsigned vb = __float_as_uint(rb); vb += 0x7fffu + ((vb >> 16) & 1u);
    lo = (va >> 16) | (vb & 0xffff0000u);
}

} // namespace

// LDS layout (ushort units), one KT=16 slab, frag-ordered so each MFMA frag
// is 16 contiguous bytes per lane (lane-linear ds_read_b128, conflict-free):
//   A: idx(tt,p,mt,kh,m32,j) = ((((tt*2+p)*2+mt)*2+kh)*32+m32)*8+j   [0,4096)
//   W: 4096 + idx(g,p,nt,kh,n32,j)                                    [4096,16384)
__global__ __launch_bounds__(256, 2) void qgru_mfma(
    const float* __restrict__ x, const float* __restrict__ hid,
    const float* __restrict__ wih, const float* __restrict__ whh,
    const float* __restrict__ bih, const float* __restrict__ bhh,
    float* __restrict__ out)
{
    __shared__ __align__(16) unsigned short lds[16384];   // 32 KB

    const int t    = threadIdx.x;
    const int lane = t & 63;
    const int wid  = t >> 6;
    const int mt   = wid >> 1;      // wave's 32-row m sub-tile (0..1)
    const int nt   = wid & 1;       // wave's 32-col n sub-tile (0..1)
    const int m0   = blockIdx.x * BM;
    const int n0   = blockIdx.y * BN;

    // staging coords: thread t handles row s_r (m or n), k-quad s_k
    const int s_r   = t >> 2;          // 0..63
    const int s_k   = (t & 3) << 2;    // 0,4,8,12
    const int s_kh  = s_k >> 3;        // k-half (0..1)
    const int s_j   = s_k & 7;         // 0 or 4
    const int s_rt  = s_r >> 5;        // row-tile of staged row
    const int s_r32 = s_r & 31;

    const float* gA[2];
    gA[0] = x   + (size_t)(m0 + s_r) * Ksz + s_k;
    gA[1] = hid + (size_t)(m0 + s_r) * Ksz + s_k;
    const float* gW[6];
#pragma unroll
    for (int g = 0; g < 3; ++g) {
        gW[g]     = wih + (size_t)(g * Hsz + n0 + s_r) * Ksz + s_k;
        gW[g + 3] = whh + (size_t)(g * Hsz + n0 + s_r) * Ksz + s_k;
    }

    const int lh  = lane >> 5;   // k-half for frag reads
    const int l32 = lane & 31;

    f32x16 acc[6];
#pragma unroll
    for (int g = 0; g < 6; ++g)
#pragma unroll
        for (int i = 0; i < 16; ++i) acc[g][i] = 0.0f;

    // prefetch k=0 slab
    float4 vA[2], vW[6];
#pragma unroll
    for (int tt = 0; tt < 2; ++tt) vA[tt] = *(const float4*)gA[tt];
#pragma unroll
    for (int g = 0; g < 6; ++g)    vW[g]  = *(const float4*)gW[g];

    for (int k0 = 0; k0 < Ksz; k0 += KT) {
        __syncthreads();   // prior iteration's frag reads complete

        // ---- convert + stage current slab ----
#pragma unroll
        for (int tt = 0; tt < 2; ++tt) {
            unsigned h0, h1, l0, l1;
            split2(vA[tt].x, vA[tt].y, h0, l0);
            split2(vA[tt].z, vA[tt].w, h1, l1);
            unsigned baseH = ((((tt * 2 + 0) * 2 + s_rt) * 2 + s_kh) * 32 + s_r32) * 8 + s_j;
            unsigned baseL = ((((tt * 2 + 1) * 2 + s_rt) * 2 + s_kh) * 32 + s_r32) * 8 + s_j;
            *reinterpret_cast<uint2*>(&lds[baseH]) = make_uint2(h0, h1);
            *reinterpret_cast<uint2*>(&lds[baseL]) = make_uint2(l0, l1);
        }
#pragma unroll
        for (int g = 0; g < 6; ++g) {
            unsigned h0, h1, l0, l1;
            split2(vW[g].x, vW[g].y, h0, l0);
            split2(vW[g].z, vW[g].w, h1, l1);
            unsigned baseH = 4096u + ((((g * 2 + 0) * 2 + s_rt) * 2 + s_kh) * 32 + s_r32) * 8 + s_j;
            unsigned baseL = 4096u + ((((g * 2 + 1) * 2 + s_rt) * 2 + s_kh) * 32 + s_r32) * 8 + s_j;
            *reinterpret_cast<uint2*>(&lds[baseH]) = make_uint2(h0, h1);
            *reinterpret_cast<uint2*>(&lds[baseL]) = make_uint2(l0, l1);
        }
        __syncthreads();

        // ---- prefetch next slab (overlaps with MFMA below) ----
        const int kn = (k0 + KT < Ksz) ? (k0 + KT) : 0;  // last-iter reload of k=0, harmless
#pragma unroll
        for (int tt = 0; tt < 2; ++tt) vA[tt] = *(const float4*)(gA[tt] + kn);
#pragma unroll
        for (int g = 0; g < 6; ++g)    vW[g]  = *(const float4*)(gW[g] + kn);

        // ---- frag reads + MFMA (bf16x3) ----
        const bf16x8 ax_hi = *reinterpret_cast<const bf16x8*>(
            &lds[((((0 * 2 + 0) * 2 + mt) * 2 + lh) * 32 + l32) * 8]);
        const bf16x8 ax_lo = *reinterpret_cast<const bf16x8*>(
            &lds[((((0 * 2 + 1) * 2 + mt) * 2 + lh) * 32 + l32) * 8]);
        const bf16x8 ah_hi = *reinterpret_cast<const bf16x8*>(
            &lds[((((1 * 2 + 0) * 2 + mt) * 2 + lh) * 32 + l32) * 8]);
        const bf16x8 ah_lo = *reinterpret_cast<const bf16x8*>(
            &lds[((((1 * 2 + 1) * 2 + mt) * 2 + lh) * 32 + l32) * 8]);

#pragma unroll
        for (int g = 0; g < 6; ++g) {
            const bf16x8 b_hi = *reinterpret_cast<const bf16x8*>(
                &lds[4096u + ((((g * 2 + 0) * 2 + nt) * 2 + lh) * 32 + l32) * 8]);
            const bf16x8 b_lo = *reinterpret_cast<const bf16x8*>(
                &lds[4096u + ((((g * 2 + 1) * 2 + nt) * 2 + lh) * 32 + l32) * 8]);
            const bf16x8 a_hi = (g < 3) ? ax_hi : ah_hi;
            const bf16x8 a_lo = (g < 3) ? ax_lo : ah_lo;
            acc[g] = __builtin_amdgcn_mfma_f32_32x32x16_bf16(a_hi, b_hi, acc[g], 0, 0, 0);
            acc[g] = __builtin_amdgcn_mfma_f32_32x32x16_bf16(a_hi, b_lo, acc[g], 0, 0, 0);
            acc[g] = __builtin_amdgcn_mfma_f32_32x32x16_bf16(a_lo, b_hi, acc[g], 0, 0, 0);
        }
    }

    // ---- epilogue: quantized GRU gate chain ----
    constexpr float S14 = 16384.0f,     I14 = 1.0f / 16384.0f;
    constexpr float S15 = 32768.0f,     I15 = 1.0f / 32768.0f;
    constexpr float S27 = 134217728.0f, I27 = 1.0f / 134217728.0f;

    const int n = n0 + nt * 32 + l32;      // output column (fixed per lane)
    const float br = bih[n], bi = bih[n + 512], bn = bih[n + 1024];
    const float cr = bhh[n], ci = bhh[n + 512], cn = bhh[n + 1024];

#pragma unroll
    for (int r = 0; r < 16; ++r) {
        const int row = (r & 3) + 8 * (r >> 2) + 4 * lh;
        const int m   = m0 + mt * 32 + row;
        const float hv = hid[(size_t)m * Hsz + n];

        float gir = qround(acc[0][r] + br, S14, I14);
        float gii = qround(acc[1][r] + bi, S14, I14);
        float gin = qround(acc[2][r] + bn, S14, I14);
        float ghr = qround(acc[3][r] + cr, S14, I14);
        float ghi = qround(acc[4][r] + ci, S14, I14);
        float ghn = qround(acc[5][r] + cn, S14, I14);
        float resetg = qsigmoid_dev(gir + ghr);
        float inputg = qsigmoid_dev(gii + ghi);
        float hn  = qround(ghn, S27, I27);
        float rh  = qround(resetg * hn, S15, I15);
        float newg = qtanh_dev(rh + gin);
        float nh  = qround(hv, S15, I15);
        out[(size_t)m * Hsz + n] = newg + inputg * (nh - newg);
    }
}

extern "C" void kernel_launch(void* const* d_in, const int* in_sizes, int n_in,
                              void* d_out, int out_size, void* d_ws, size_t ws_size,
                              hipStream_t stream) {
    const float* x   = (const float*)d_in[0];
    const float* hid = (const float*)d_in[1];
    const float* wih = (const float*)d_in[2];
    const float* whh = (const float*)d_in[3];
    const float* bih = (const float*)d_in[4];
    const float* bhh = (const float*)d_in[5];
    float* out = (float*)d_out;

    dim3 grid(Bsz / BM, Hsz / BN);   // (128, 8): x-major -> consecutive blocks
                                     // share weight tiles in L2
    qgru_mfma<<<grid, dim3(256), 0, stream>>>(x, hid, wih, whh, bih, bhh, out);
}

// Round 4
// 168.823 us; speedup vs baseline: 2.3428x; 1.3069x over previous
//
#include <hip/hip_runtime.h>
#include <math.h>

// QGRUCell — Round 4: f16 single-pass MFMA + global_load_lds DMA staging.
// Pre-pass converts x/h/[wih;whh] to f16 in d_ws; main kernel is an
// m97-style GEMM (async 16B DMA staging, lane-linear LDS, KT=32) with the
// validated quantized-gate epilogue. Round-3 bf16x3 kernel kept as fallback
// if ws_size is too small.

typedef _Float16 f16x8  __attribute__((ext_vector_type(8)));
typedef __bf16   bf16x8 __attribute__((ext_vector_type(8)));
typedef float    f32x16 __attribute__((ext_vector_type(16)));

namespace {

constexpr int Bsz = 8192, Ksz = 512, Hsz = 512;
constexpr int BM = 64, BN = 64, KT = 32;

// ws layout (f16 units): [x 8192x512][h 8192x512][wih;whh as 3072x512]
constexpr unsigned X0  = 0;
constexpr unsigned Hh0 = 8192u * 512u;            // 4194304
constexpr unsigned W0  = 2u * 8192u * 512u;       // 8388608
constexpr unsigned WS_F16  = W0 + 3072u * 512u;   // 9961472 f16 elements
constexpr size_t   WS_NEED = (size_t)WS_F16 * 2;  // 19,922,944 bytes

__device__ __forceinline__ float qround(float x, float s, float invs) {
    return floorf(x * s + 0.5f) * invs;
}

__device__ __forceinline__ float qsigmoid_dev(float x) {
    float iq = floorf(x * 134217728.0f + 0.5f);
    iq = fminf(fmaxf(iq, -2147483648.0f), 2147483648.0f);
    float s  = 1.0f / (1.0f + expf(-iq * 7.450580596923828125e-9f));
    float q31 = floorf(s * 2147483648.0f + 0.5f);
    float q15 = floorf(q31 * 1.52587890625e-5f + 0.5f);
    return q15 * 3.0517578125e-5f;
}

__device__ __forceinline__ float qtanh_dev(float x) {
    float iq = floorf(x * 134217728.0f + 0.5f);
    iq = fminf(fmaxf(iq, -2147483648.0f), 2147483648.0f);
    float tv = tanhf(iq * 7.450580596923828125e-9f);
    float q31 = floorf(tv * 2147483648.0f + 0.5f);
    float q15 = floorf(q31 * 1.52587890625e-5f + 0.5f);
    return q15 * 3.0517578125e-5f;
}

__device__ __forceinline__ unsigned short f2h(float f) {
    _Float16 h = (_Float16)f;
    unsigned short s;
    __builtin_memcpy(&s, &h, 2);
    return s;
}

__device__ __forceinline__ void dma16(const void* g, void* l) {
    __builtin_amdgcn_global_load_lds(
        (const __attribute__((address_space(1))) unsigned int*)g,
        (__attribute__((address_space(3))) unsigned int*)l, 16, 0, 0);
}

// bf16 split for fallback kernel
__device__ __forceinline__ void split2(float a, float b, unsigned& hi, unsigned& lo) {
    unsigned ua = __float_as_uint(a); ua += 0x7fffu + ((ua >> 16) & 1u);
    unsigned ub = __float_as_uint(b); ub += 0x7fffu + ((ub >> 16) & 1u);
    hi = (ua >> 16) | (ub & 0xffff0000u);
    float ra = a - __uint_as_float(ua & 0xffff0000u);
    float rb = b - __uint_as_float(ub & 0xffff0000u);
    unsigned va = __float_as_uint(ra); va += 0x7fffu + ((va >> 16) & 1u);
    unsigned vb = __float_as_uint(rb); vb += 0x7fffu + ((vb >> 16) & 1u);
    lo = (va >> 16) | (vb & 0xffff0000u);
}

} // namespace

// ---------------- pre-pass: fp32 -> f16 into ws ----------------
__global__ __launch_bounds__(256) void cvt_f16(
    const float* __restrict__ x, const float* __restrict__ h,
    const float* __restrict__ wih, const float* __restrict__ whh,
    _Float16* __restrict__ ws)
{
    const unsigned qi = blockIdx.x * 256u + threadIdx.x;   // float4 index
    const unsigned QX = 8192u * 512u / 4u;                 // 1048576
    const unsigned QW = 1536u * 512u / 4u;                 // 196608
    const float4* src;
    if      (qi < QX)           src = (const float4*)x   + qi;
    else if (qi < 2u*QX)        src = (const float4*)h   + (qi - QX);
    else if (qi < 2u*QX + QW)   src = (const float4*)wih + (qi - 2u*QX);
    else                        src = (const float4*)whh + (qi - 2u*QX - QW);
    float4 v = *src;
    uint2 p;
    p.x = (unsigned)f2h(v.x) | ((unsigned)f2h(v.y) << 16);
    p.y = (unsigned)f2h(v.z) | ((unsigned)f2h(v.w) << 16);
    ((uint2*)ws)[qi] = p;
}

// ---------------- main: f16 MFMA GEMM + fused epilogue ----------------
// LDS (f16 units, 32 KB): A chunk(m,mt,ks2) at (m*2+mt)*1024 + ks2*512,
// W chunk(g,nt,ks2) at 4096 + (g*2+nt)*1024 + ks2*512. Each chunk = 1 KB,
// DMA lane i writes chunk_base + i*16B; frag reads are lane-linear b128.
__global__ __launch_bounds__(256, 3) void qgru_f16_dma(
    const _Float16* __restrict__ ws, const float* __restrict__ hid,
    const float* __restrict__ bih, const float* __restrict__ bhh,
    float* __restrict__ out)
{
    __shared__ __align__(16) _Float16 lds[16384];   // 32 KB

    const int t = threadIdx.x, lane = t & 63, wid = t >> 6;
    const int mt = wid >> 1, nt = wid & 1;
    const int m0 = blockIdx.x * BM, n0 = blockIdx.y * BN;
    const int lr = lane & 31, lk8 = (lane >> 5) * 8;

    // per-wave DMA chunk tables (8 chunks of 1 KB per wave)
    unsigned goff[8];   // per-lane global byte offset into ws
    int      ldst[8];   // wave-uniform LDS f16 index
    if (wid == 0) {     // all A chunks: c = m*4 + mtc*2 + ks2
#pragma unroll
        for (int c = 0; c < 8; ++c) {
            int m = c >> 2, mtc = (c >> 1) & 1, ks2 = c & 1;
            goff[c] = 2u * ((m ? Hh0 : X0)
                      + (unsigned)(m0 + mtc * 32 + lr) * 512u + ks2 * 16 + lk8);
            ldst[c] = (m * 2 + mtc) * 1024 + ks2 * 512;
        }
    } else {            // W chunks: wave w covers gates 2(w-1), 2(w-1)+1
#pragma unroll
        for (int c = 0; c < 8; ++c) {
            int g = (wid - 1) * 2 + (c >> 2), ntc = (c >> 1) & 1, ks2 = c & 1;
            // combined [wih;whh] row for gate g, col n is g*512 + n
            goff[c] = 2u * (W0
                      + (unsigned)(g * 512 + n0 + ntc * 32 + lr) * 512u + ks2 * 16 + lk8);
            ldst[c] = 4096 + (g * 2 + ntc) * 1024 + ks2 * 512;
        }
    }

    f32x16 acc[6];
#pragma unroll
    for (int g = 0; g < 6; ++g)
#pragma unroll
        for (int i = 0; i < 16; ++i) acc[g][i] = 0.0f;

    const char* wsb = (const char*)ws;
    for (int k0 = 0; k0 < Ksz; k0 += KT) {
        const unsigned kb = (unsigned)k0 * 2u;
#pragma unroll
        for (int c = 0; c < 8; ++c)
            dma16(wsb + goff[c] + kb, &lds[ldst[c]]);
        __syncthreads();   // drains vmcnt -> slab resident

#pragma unroll
        for (int ks2 = 0; ks2 < 2; ++ks2) {
            const int lfo = ks2 * 512 + lk8 * 32 + lr * 8;   // lane frag offset
            const f16x8 ax = *(const f16x8*)&lds[(0 + mt) * 1024 + lfo];
            const f16x8 ah = *(const f16x8*)&lds[(2 + mt) * 1024 + lfo];
#pragma unroll
            for (int g = 0; g < 6; ++g) {
                const f16x8 b = *(const f16x8*)&lds[4096 + (g * 2 + nt) * 1024 + lfo];
                acc[g] = __builtin_amdgcn_mfma_f32_32x32x16_f16(
                             g < 3 ? ax : ah, b, acc[g], 0, 0, 0);
            }
        }
        __syncthreads();   // frag reads done before next DMA overwrite
    }

    // ---- epilogue: quantized GRU gate chain (validated in rounds 1-3) ----
    constexpr float S14 = 16384.0f,     I14 = 1.0f / 16384.0f;
    constexpr float S15 = 32768.0f,     I15 = 1.0f / 32768.0f;
    constexpr float S27 = 134217728.0f, I27 = 1.0f / 134217728.0f;

    const int lh = lane >> 5, l32 = lane & 31;
    const int n = n0 + nt * 32 + l32;
    const float br = bih[n], bi = bih[n + 512], bn = bih[n + 1024];
    const float cr = bhh[n], ci = bhh[n + 512], cn = bhh[n + 1024];

#pragma unroll
    for (int r = 0; r < 16; ++r) {
        const int row = (r & 3) + 8 * (r >> 2) + 4 * lh;
        const int m   = m0 + mt * 32 + row;
        const float hv = hid[(size_t)m * Hsz + n];

        float gir = qround(acc[0][r] + br, S14, I14);
        float gii = qround(acc[1][r] + bi, S14, I14);
        float gin = qround(acc[2][r] + bn, S14, I14);
        float ghr = qround(acc[3][r] + cr, S14, I14);
        float ghi = qround(acc[4][r] + ci, S14, I14);
        float ghn = qround(acc[5][r] + cn, S14, I14);
        float resetg = qsigmoid_dev(gir + ghr);
        float inputg = qsigmoid_dev(gii + ghi);
        float hn  = qround(ghn, S27, I27);
        float rh  = qround(resetg * hn, S15, I15);
        float newg = qtanh_dev(rh + gin);
        float nh  = qround(hv, S15, I15);
        out[(size_t)m * Hsz + n] = newg + inputg * (nh - newg);
    }
}

// ---------------- fallback: round-3 bf16x3 (self-contained) ----------------
__global__ __launch_bounds__(256, 2) void qgru_mfma_bf16x3(
    const float* __restrict__ x, const float* __restrict__ hid,
    const float* __restrict__ wih, const float* __restrict__ whh,
    const float* __restrict__ bih, const float* __restrict__ bhh,
    float* __restrict__ out)
{
    __shared__ __align__(16) unsigned short lds[16384];

    const int t = threadIdx.x, lane = t & 63, wid = t >> 6;
    const int mt = wid >> 1, nt = wid & 1;
    const int m0 = blockIdx.x * BM, n0 = blockIdx.y * BN;
    const int s_r = t >> 2, s_k = (t & 3) << 2;
    const int s_kh = s_k >> 3, s_j = s_k & 7, s_rt = s_r >> 5, s_r32 = s_r & 31;

    const float* gA[2];
    gA[0] = x   + (size_t)(m0 + s_r) * Ksz + s_k;
    gA[1] = hid + (size_t)(m0 + s_r) * Ksz + s_k;
    const float* gW[6];
#pragma unroll
    for (int g = 0; g < 3; ++g) {
        gW[g]     = wih + (size_t)(g * Hsz + n0 + s_r) * Ksz + s_k;
        gW[g + 3] = whh + (size_t)(g * Hsz + n0 + s_r) * Ksz + s_k;
    }
    const int lh = lane >> 5, l32 = lane & 31;

    f32x16 acc[6];
#pragma unroll
    for (int g = 0; g < 6; ++g)
#pragma unroll
        for (int i = 0; i < 16; ++i) acc[g][i] = 0.0f;

    float4 vA[2], vW[6];
#pragma unroll
    for (int tt = 0; tt < 2; ++tt) vA[tt] = *(const float4*)gA[tt];
#pragma unroll
    for (int g = 0; g < 6; ++g)    vW[g]  = *(const float4*)gW[g];

    for (int k0 = 0; k0 < Ksz; k0 += 16) {
        __syncthreads();
#pragma unroll
        for (int tt = 0; tt < 2; ++tt) {
            unsigned h0, h1, l0, l1;
            split2(vA[tt].x, vA[tt].y, h0, l0);
            split2(vA[tt].z, vA[tt].w, h1, l1);
            unsigned bH = ((((tt*2+0)*2+s_rt)*2+s_kh)*32+s_r32)*8 + s_j;
            unsigned bL = ((((tt*2+1)*2+s_rt)*2+s_kh)*32+s_r32)*8 + s_j;
            *reinterpret_cast<uint2*>(&lds[bH]) = make_uint2(h0, h1);
            *reinterpret_cast<uint2*>(&lds[bL]) = make_uint2(l0, l1);
        }
#pragma unroll
        for (int g = 0; g < 6; ++g) {
            unsigned h0, h1, l0, l1;
            split2(vW[g].x, vW[g].y, h0, l0);
            split2(vW[g].z, vW[g].w, h1, l1);
            unsigned bH = 4096u + ((((g*2+0)*2+s_rt)*2+s_kh)*32+s_r32)*8 + s_j;
            unsigned bL = 4096u + ((((g*2+1)*2+s_rt)*2+s_kh)*32+s_r32)*8 + s_j;
            *reinterpret_cast<uint2*>(&lds[bH]) = make_uint2(h0, h1);
            *reinterpret_cast<uint2*>(&lds[bL]) = make_uint2(l0, l1);
        }
        __syncthreads();
        const int kn = (k0 + 16 < Ksz) ? (k0 + 16) : 0;
#pragma unroll
        for (int tt = 0; tt < 2; ++tt) vA[tt] = *(const float4*)(gA[tt] + kn);
#pragma unroll
        for (int g = 0; g < 6; ++g)    vW[g]  = *(const float4*)(gW[g] + kn);

        const bf16x8 ax_hi = *reinterpret_cast<const bf16x8*>(&lds[((((0)*2+mt)*2+lh)*32+l32)*8]);
        const bf16x8 ax_lo = *reinterpret_cast<const bf16x8*>(&lds[((((1)*2+mt)*2+lh)*32+l32)*8]);
        const bf16x8 ah_hi = *reinterpret_cast<const bf16x8*>(&lds[((((2)*2+mt)*2+lh)*32+l32)*8]);
        const bf16x8 ah_lo = *reinterpret_cast<const bf16x8*>(&lds[((((3)*2+mt)*2+lh)*32+l32)*8]);
#pragma unroll
        for (int g = 0; g < 6; ++g) {
            const bf16x8 b_hi = *reinterpret_cast<const bf16x8*>(&lds[4096u + ((((g*2+0)*2+nt)*2+lh)*32+l32)*8]);
            const bf16x8 b_lo = *reinterpret_cast<const bf16x8*>(&lds[4096u + ((((g*2+1)*2+nt)*2+lh)*32+l32)*8]);
            const bf16x8 a_hi = (g < 3) ? ax_hi : ah_hi;
            const bf16x8 a_lo = (g < 3) ? ax_lo : ah_lo;
            acc[g] = __builtin_amdgcn_mfma_f32_32x32x16_bf16(a_hi, b_hi, acc[g], 0, 0, 0);
            acc[g] = __builtin_amdgcn_mfma_f32_32x32x16_bf16(a_hi, b_lo, acc[g], 0, 0, 0);
            acc[g] = __builtin_amdgcn_mfma_f32_32x32x16_bf16(a_lo, b_hi, acc[g], 0, 0, 0);
        }
    }

    constexpr float S14 = 16384.0f,     I14 = 1.0f / 16384.0f;
    constexpr float S15 = 32768.0f,     I15 = 1.0f / 32768.0f;
    constexpr float S27 = 134217728.0f, I27 = 1.0f / 134217728.0f;
    const int n = n0 + nt * 32 + l32;
    const float br = bih[n], bi = bih[n + 512], bn = bih[n + 1024];
    const float cr = bhh[n], ci = bhh[n + 512], cn = bhh[n + 1024];
#pragma unroll
    for (int r = 0; r < 16; ++r) {
        const int row = (r & 3) + 8 * (r >> 2) + 4 * lh;
        const int m   = m0 + mt * 32 + row;
        const float hv = hid[(size_t)m * Hsz + n];
        float gir = qround(acc[0][r] + br, S14, I14);
        float gii = qround(acc[1][r] + bi, S14, I14);
        float gin = qround(acc[2][r] + bn, S14, I14);
        float ghr = qround(acc[3][r] + cr, S14, I14);
        float ghi = qround(acc[4][r] + ci, S14, I14);
        float ghn = qround(acc[5][r] + cn, S14, I14);
        float resetg = qsigmoid_dev(gir + ghr);
        float inputg = qsigmoid_dev(gii + ghi);
        float hn  = qround(ghn, S27, I27);
        float rh  = qround(resetg * hn, S15, I15);
        float newg = qtanh_dev(rh + gin);
        float nh  = qround(hv, S15, I15);
        out[(size_t)m * Hsz + n] = newg + inputg * (nh - newg);
    }
}

extern "C" void kernel_launch(void* const* d_in, const int* in_sizes, int n_in,
                              void* d_out, int out_size, void* d_ws, size_t ws_size,
                              hipStream_t stream) {
    const float* x   = (const float*)d_in[0];
    const float* hid = (const float*)d_in[1];
    const float* wih = (const float*)d_in[2];
    const float* whh = (const float*)d_in[3];
    const float* bih = (const float*)d_in[4];
    const float* bhh = (const float*)d_in[5];
    float* out = (float*)d_out;
    dim3 grid(Bsz / BM, Hsz / BN);   // x-major: consecutive blocks share W tiles

    if (ws_size >= WS_NEED) {
        cvt_f16<<<WS_F16 / 4 / 256, 256, 0, stream>>>(x, hid, wih, whh, (_Float16*)d_ws);
        qgru_f16_dma<<<grid, dim3(256), 0, stream>>>(
            (const _Float16*)d_ws, hid, bih, bhh, out);
    } else {
        qgru_mfma_bf16x3<<<grid, dim3(256), 0, stream>>>(
            x, hid, wih, whh, bih, bhh, out);
    }
}

// Round 5
// 131.891 us; speedup vs baseline: 2.9988x; 1.2800x over previous
//
#include <hip/hip_runtime.h>
#include <math.h>

// QGRUCell — Round 5: pre-tiled f16 workspace + contiguous 1KB DMA chunks +
// double-buffered LDS (one barrier per K-step) + fast-exp epilogue.
// ws holds x/h/[wih;whh] as f16 in MFMA-frag-ordered 512-element chunks, so
// each global_load_lds reads 16 fully-used cache lines (was 32 half-used).

typedef _Float16 f16x8  __attribute__((ext_vector_type(8)));
typedef __bf16   bf16x8 __attribute__((ext_vector_type(8)));
typedef float    f32x16 __attribute__((ext_vector_type(16)));

namespace {

constexpr int Bsz = 8192, Ksz = 512, Hsz = 512;
constexpr int BM = 64, BN = 64, KT = 32;

// ws (f16 units): chunks of 512 f16 (32 rows x 16 k, frag order:
// pos(row,k) = (k>>3)*256 + row*8 + (k&7)).
// A region: chunk(arr, M32, K16) = arr*8192 + M32*32 + K16     [16384 chunks]
// W region: 16384 + chunk(g, N32, K16) = (g*16+N32)*32 + K16   [3072 chunks]
constexpr unsigned WCH0    = 16384u;                  // first W chunk index
constexpr unsigned WS_F16  = (16384u + 3072u) * 512u; // 9,961,472 f16
constexpr size_t   WS_NEED = (size_t)WS_F16 * 2;      // 19,922,944 B

__device__ __forceinline__ float qround(float x, float s, float invs) {
    return floorf(x * s + 0.5f) * invs;
}

__device__ __forceinline__ float qsigmoid_dev(float x) {
    float iq = floorf(x * 134217728.0f + 0.5f);
    iq = fminf(fmaxf(iq, -2147483648.0f), 2147483648.0f);
    float e = __expf(-iq * 7.450580596923828125e-9f);
    float s = __builtin_amdgcn_rcpf(1.0f + e);          // ~1 ulp; q15 flip prob <1%
    float q31 = floorf(s * 2147483648.0f + 0.5f);
    float q15 = floorf(q31 * 1.52587890625e-5f + 0.5f);
    return q15 * 3.0517578125e-5f;
}

__device__ __forceinline__ float qtanh_dev(float x) {
    float iq = floorf(x * 134217728.0f + 0.5f);
    iq = fminf(fmaxf(iq, -2147483648.0f), 2147483648.0f);
    float z = iq * 7.450580596923828125e-9f;
    float e = __expf(2.0f * z);                         // tanh = 1 - 2/(e^2z+1)
    float t = 1.0f - 2.0f * __builtin_amdgcn_rcpf(e + 1.0f);
    float q31 = floorf(t * 2147483648.0f + 0.5f);
    float q15 = floorf(q31 * 1.52587890625e-5f + 0.5f);
    return q15 * 3.0517578125e-5f;
}

__device__ __forceinline__ void dma16(const void* g, void* l) {
    __builtin_amdgcn_global_load_lds(
        (const __attribute__((address_space(1))) unsigned int*)g,
        (__attribute__((address_space(3))) unsigned int*)l, 16, 0, 0);
}

// bf16 split for fallback kernel
__device__ __forceinline__ void split2(float a, float b, unsigned& hi, unsigned& lo) {
    unsigned ua = __float_as_uint(a); ua += 0x7fffu + ((ua >> 16) & 1u);
    unsigned ub = __float_as_uint(b); ub += 0x7fffu + ((ub >> 16) & 1u);
    hi = (ua >> 16) | (ub & 0xffff0000u);
    float ra = a - __uint_as_float(ua & 0xffff0000u);
    float rb = b - __uint_as_float(ub & 0xffff0000u);
    unsigned va = __float_as_uint(ra); va += 0x7fffu + ((va >> 16) & 1u);
    unsigned vb = __float_as_uint(rb); vb += 0x7fffu + ((vb >> 16) & 1u);
    lo = (va >> 16) | (vb & 0xffff0000u);
}

} // namespace

// ---------------- pre-pass: fp32 -> f16, tiled into frag-order chunks ------
// One wave per source row (fully coalesced 2KB read); lane l converts k-octet
// [8l, 8l+8) and writes one 16B piece at its chunk position.
__global__ __launch_bounds__(256) void cvt_tile_f16(
    const float* __restrict__ x, const float* __restrict__ h,
    const float* __restrict__ wih, const float* __restrict__ whh,
    _Float16* __restrict__ ws)
{
    const int row  = blockIdx.x * 4 + (threadIdx.x >> 6);   // 0..19455
    const int lane = threadIdx.x & 63;
    const float* src;
    unsigned chunk0;   // chunk index at K16=0
    unsigned rin;      // row-in-chunk
    if (row < 8192) {                                        // x  (arr 0)
        src = x + (size_t)row * 512;
        chunk0 = (unsigned)(row >> 5) * 32u;
        rin = row & 31;
    } else if (row < 16384) {                                // h  (arr 1)
        int r = row - 8192;
        src = h + (size_t)r * 512;
        chunk0 = 8192u + (unsigned)(r >> 5) * 32u;
        rin = r & 31;
    } else {                                                 // weights
        int w = row - 16384;                                 // 0..3071
        int g, n;
        if (w < 1536) { g = w >> 9;        n = w & 511;  src = wih + (size_t)w * 512; }
        else { int v = w - 1536; g = 3 + (v >> 9); n = v & 511; src = whh + (size_t)v * 512; }
        chunk0 = WCH0 + (unsigned)((g * 16 + (n >> 5)) * 32);
        rin = n & 31;
    }
    const int K16 = lane >> 1, kh = lane & 1;
    float4 v0 = *(const float4*)(src + lane * 8);
    float4 v1 = *(const float4*)(src + lane * 8 + 4);
    f16x8 o;
    o[0] = (_Float16)v0.x; o[1] = (_Float16)v0.y;
    o[2] = (_Float16)v0.z; o[3] = (_Float16)v0.w;
    o[4] = (_Float16)v1.x; o[5] = (_Float16)v1.y;
    o[6] = (_Float16)v1.z; o[7] = (_Float16)v1.w;
    *(f16x8*)(ws + (size_t)(chunk0 + K16) * 512u + kh * 256 + rin * 8) = o;
}

// ---------------- main: f16 MFMA GEMM, dbuf LDS, fused epilogue ------------
// Slab (16384 f16 = 32KB): A chunk (arr*2+mtc)*1024 + ks2*512  [0,4096)
//                          W chunk 4096 + (g*2+nt)*1024 + ks2*512
// Two slabs; one __syncthreads per K-step; prefetch issued after the barrier
// so the next barrier's vmcnt(0) drain overlaps this step's compute.
__global__ __launch_bounds__(256, 2) void qgru_f16_dma2(
    const _Float16* __restrict__ ws, const float* __restrict__ hid,
    const float* __restrict__ bih, const float* __restrict__ bhh,
    float* __restrict__ out)
{
    __shared__ __align__(16) _Float16 lds[32768];   // 64 KB (2 slabs)

    const int t = threadIdx.x, lane = t & 63, wid = t >> 6;
    const int mt = wid >> 1, nt = wid & 1;
    const int m0 = blockIdx.x * BM, n0 = blockIdx.y * BN;

    // per-wave DMA tables: 8 chunks/wave; goff = ws byte offset at K16=ks2
    unsigned goff[8];
    int      ldst[8];   // slab-relative LDS f16 index
    if (wid == 0) {     // A chunks: c = arr*4 + mtc*2 + ks2
#pragma unroll
        for (int c = 0; c < 8; ++c) {
            int arr = c >> 2, mtc = (c >> 1) & 1, ks2 = c & 1;
            unsigned ch = (unsigned)arr * 8192u
                        + (unsigned)((m0 >> 5) + mtc) * 32u + (unsigned)ks2;
            goff[c] = ch * 1024u + (unsigned)lane * 16u;   // bytes
            ldst[c] = (arr * 2 + mtc) * 1024 + ks2 * 512;
        }
    } else {            // W chunks: wave w covers gates 2(w-1), 2(w-1)+1
#pragma unroll
        for (int c = 0; c < 8; ++c) {
            int g = (wid - 1) * 2 + (c >> 2), ntc = (c >> 1) & 1, ks2 = c & 1;
            unsigned ch = WCH0
                        + (unsigned)((g * 16 + (n0 >> 5) + ntc) * 32) + (unsigned)ks2;
            goff[c] = ch * 1024u + (unsigned)lane * 16u;
            ldst[c] = 4096 + (g * 2 + ntc) * 1024 + ks2 * 512;
        }
    }

    f32x16 acc[6];
#pragma unroll
    for (int g = 0; g < 6; ++g)
#pragma unroll
        for (int i = 0; i < 16; ++i) acc[g][i] = 0.0f;

    const char* wsb = (const char*)ws;
    const int lr = lane & 31, lk8 = (lane >> 5) * 8;

    // pre-issue step 0 into slab 0
#pragma unroll
    for (int c = 0; c < 8; ++c)
        dma16(wsb + goff[c], &lds[ldst[c]]);

    for (int step = 0; step < 16; ++step) {
        __syncthreads();   // drains DMA for current slab; prev compute done

        if (step + 1 < 16) {
            const unsigned kb = (unsigned)(step + 1) * 2048u;  // 2 chunks/step
            const int nb = ((step + 1) & 1) * 16384;
#pragma unroll
            for (int c = 0; c < 8; ++c)
                dma16(wsb + goff[c] + kb, &lds[nb + ldst[c]]);
        }

        const int cb = (step & 1) * 16384;
#pragma unroll
        for (int ks2 = 0; ks2 < 2; ++ks2) {
            const int lfo = cb + ks2 * 512 + lk8 * 32 + lr * 8;
            const f16x8 ax = *(const f16x8*)&lds[lfo + (0 + mt) * 1024];
            const f16x8 ah = *(const f16x8*)&lds[lfo + (2 + mt) * 1024];
#pragma unroll
            for (int g = 0; g < 6; ++g) {
                const f16x8 b = *(const f16x8*)&lds[lfo + 4096 + (g * 2 + nt) * 1024];
                acc[g] = __builtin_amdgcn_mfma_f32_32x32x16_f16(
                             g < 3 ? ax : ah, b, acc[g], 0, 0, 0);
            }
        }
    }

    // ---- epilogue: quantized GRU gate chain ----
    constexpr float S14 = 16384.0f,     I14 = 1.0f / 16384.0f;
    constexpr float S15 = 32768.0f,     I15 = 1.0f / 32768.0f;
    constexpr float S27 = 134217728.0f, I27 = 1.0f / 134217728.0f;

    const int lh = lane >> 5, l32 = lane & 31;
    const int n = n0 + nt * 32 + l32;
    const float br = bih[n], bi = bih[n + 512], bn = bih[n + 1024];
    const float cr = bhh[n], ci = bhh[n + 512], cn = bhh[n + 1024];

#pragma unroll
    for (int r = 0; r < 16; ++r) {
        const int row = (r & 3) + 8 * (r >> 2) + 4 * lh;
        const int m   = m0 + mt * 32 + row;
        const float hv = hid[(size_t)m * Hsz + n];

        float gir = qround(acc[0][r] + br, S14, I14);
        float gii = qround(acc[1][r] + bi, S14, I14);
        float gin = qround(acc[2][r] + bn, S14, I14);
        float ghr = qround(acc[3][r] + cr, S14, I14);
        float ghi = qround(acc[4][r] + ci, S14, I14);
        float ghn = qround(acc[5][r] + cn, S14, I14);
        float resetg = qsigmoid_dev(gir + ghr);
        float inputg = qsigmoid_dev(gii + ghi);
        float hn  = qround(ghn, S27, I27);
        float rh  = qround(resetg * hn, S15, I15);
        float newg = qtanh_dev(rh + gin);
        float nh  = qround(hv, S15, I15);
        out[(size_t)m * Hsz + n] = newg + inputg * (nh - newg);
    }
}

// ---------------- fallback: round-3 bf16x3 (used only if ws too small) -----
__global__ __launch_bounds__(256, 2) void qgru_mfma_bf16x3(
    const float* __restrict__ x, const float* __restrict__ hid,
    const float* __restrict__ wih, const float* __restrict__ whh,
    const float* __restrict__ bih, const float* __restrict__ bhh,
    float* __restrict__ out)
{
    __shared__ __align__(16) unsigned short lds[16384];

    const int t = threadIdx.x, lane = t & 63, wid = t >> 6;
    const int mt = wid >> 1, nt = wid & 1;
    const int m0 = blockIdx.x * BM, n0 = blockIdx.y * BN;
    const int s_r = t >> 2, s_k = (t & 3) << 2;
    const int s_kh = s_k >> 3, s_j = s_k & 7, s_rt = s_r >> 5, s_r32 = s_r & 31;

    const float* gA[2];
    gA[0] = x   + (size_t)(m0 + s_r) * Ksz + s_k;
    gA[1] = hid + (size_t)(m0 + s_r) * Ksz + s_k;
    const float* gW[6];
#pragma unroll
    for (int g = 0; g < 3; ++g) {
        gW[g]     = wih + (size_t)(g * Hsz + n0 + s_r) * Ksz + s_k;
        gW[g + 3] = whh + (size_t)(g * Hsz + n0 + s_r) * Ksz + s_k;
    }
    const int lh = lane >> 5, l32 = lane & 31;

    f32x16 acc[6];
#pragma unroll
    for (int g = 0; g < 6; ++g)
#pragma unroll
        for (int i = 0; i < 16; ++i) acc[g][i] = 0.0f;

    float4 vA[2], vW[6];
#pragma unroll
    for (int tt = 0; tt < 2; ++tt) vA[tt] = *(const float4*)gA[tt];
#pragma unroll
    for (int g = 0; g < 6; ++g)    vW[g]  = *(const float4*)gW[g];

    for (int k0 = 0; k0 < Ksz; k0 += 16) {
        __syncthreads();
#pragma unroll
        for (int tt = 0; tt < 2; ++tt) {
            unsigned h0, h1, l0, l1;
            split2(vA[tt].x, vA[tt].y, h0, l0);
            split2(vA[tt].z, vA[tt].w, h1, l1);
            unsigned bH = ((((tt*2+0)*2+s_rt)*2+s_kh)*32+s_r32)*8 + s_j;
            unsigned bL = ((((tt*2+1)*2+s_rt)*2+s_kh)*32+s_r32)*8 + s_j;
            *reinterpret_cast<uint2*>(&lds[bH]) = make_uint2(h0, h1);
            *reinterpret_cast<uint2*>(&lds[bL]) = make_uint2(l0, l1);
        }
#pragma unroll
        for (int g = 0; g < 6; ++g) {
            unsigned h0, h1, l0, l1;
            split2(vW[g].x, vW[g].y, h0, l0);
            split2(vW[g].z, vW[g].w, h1, l1);
            unsigned bH = 4096u + ((((g*2+0)*2+s_rt)*2+s_kh)*32+s_r32)*8 + s_j;
            unsigned bL = 4096u + ((((g*2+1)*2+s_rt)*2+s_kh)*32+s_r32)*8 + s_j;
            *reinterpret_cast<uint2*>(&lds[bH]) = make_uint2(h0, h1);
            *reinterpret_cast<uint2*>(&lds[bL]) = make_uint2(l0, l1);
        }
        __syncthreads();
        const int kn = (k0 + 16 < Ksz) ? (k0 + 16) : 0;
#pragma unroll
        for (int tt = 0; tt < 2; ++tt) vA[tt] = *(const float4*)(gA[tt] + kn);
#pragma unroll
        for (int g = 0; g < 6; ++g)    vW[g]  = *(const float4*)(gW[g] + kn);

        const bf16x8 ax_hi = *reinterpret_cast<const bf16x8*>(&lds[((((0)*2+mt)*2+lh)*32+l32)*8]);
        const bf16x8 ax_lo = *reinterpret_cast<const bf16x8*>(&lds[((((1)*2+mt)*2+lh)*32+l32)*8]);
        const bf16x8 ah_hi = *reinterpret_cast<const bf16x8*>(&lds[((((2)*2+mt)*2+lh)*32+l32)*8]);
        const bf16x8 ah_lo = *reinterpret_cast<const bf16x8*>(&lds[((((3)*2+mt)*2+lh)*32+l32)*8]);
#pragma unroll
        for (int g = 0; g < 6; ++g) {
            const bf16x8 b_hi = *reinterpret_cast<const bf16x8*>(&lds[4096u + ((((g*2+0)*2+nt)*2+lh)*32+l32)*8]);
            const bf16x8 b_lo = *reinterpret_cast<const bf16x8*>(&lds[4096u + ((((g*2+1)*2+nt)*2+lh)*32+l32)*8]);
            const bf16x8 a_hi = (g < 3) ? ax_hi : ah_hi;
            const bf16x8 a_lo = (g < 3) ? ax_lo : ah_lo;
            acc[g] = __builtin_amdgcn_mfma_f32_32x32x16_bf16(a_hi, b_hi, acc[g], 0, 0, 0);
            acc[g] = __builtin_amdgcn_mfma_f32_32x32x16_bf16(a_hi, b_lo, acc[g], 0, 0, 0);
            acc[g] = __builtin_amdgcn_mfma_f32_32x32x16_bf16(a_lo, b_hi, acc[g], 0, 0, 0);
        }
    }

    constexpr float S14 = 16384.0f,     I14 = 1.0f / 16384.0f;
    constexpr float S15 = 32768.0f,     I15 = 1.0f / 32768.0f;
    constexpr float S27 = 134217728.0f, I27 = 1.0f / 134217728.0f;
    const int n = n0 + nt * 32 + l32;
    const float br = bih[n], bi = bih[n + 512], bn = bih[n + 1024];
    const float cr = bhh[n], ci = bhh[n + 512], cn = bhh[n + 1024];
#pragma unroll
    for (int r = 0; r < 16; ++r) {
        const int row = (r & 3) + 8 * (r >> 2) + 4 * lh;
        const int m   = m0 + mt * 32 + row;
        const float hv = hid[(size_t)m * Hsz + n];
        float gir = qround(acc[0][r] + br, S14, I14);
        float gii = qround(acc[1][r] + bi, S14, I14);
        float gin = qround(acc[2][r] + bn, S14, I14);
        float ghr = qround(acc[3][r] + cr, S14, I14);
        float ghi = qround(acc[4][r] + ci, S14, I14);
        float ghn = qround(acc[5][r] + cn, S14, I14);
        float resetg = qsigmoid_dev(gir + ghr);
        float inputg = qsigmoid_dev(gii + ghi);
        float hn  = qround(ghn, S27, I27);
        float rh  = qround(resetg * hn, S15, I15);
        float newg = qtanh_dev(rh + gin);
        float nh  = qround(hv, S15, I15);
        out[(size_t)m * Hsz + n] = newg + inputg * (nh - newg);
    }
}

extern "C" void kernel_launch(void* const* d_in, const int* in_sizes, int n_in,
                              void* d_out, int out_size, void* d_ws, size_t ws_size,
                              hipStream_t stream) {
    const float* x   = (const float*)d_in[0];
    const float* hid = (const float*)d_in[1];
    const float* wih = (const float*)d_in[2];
    const float* whh = (const float*)d_in[3];
    const float* bih = (const float*)d_in[4];
    const float* bhh = (const float*)d_in[5];
    float* out = (float*)d_out;
    dim3 grid(Bsz / BM, Hsz / BN);   // x-major: consecutive blocks share W chunks

    if (ws_size >= WS_NEED) {
        cvt_tile_f16<<<19456 / 4, 256, 0, stream>>>(x, hid, wih, whh, (_Float16*)d_ws);
        qgru_f16_dma2<<<grid, dim3(256), 0, stream>>>(
            (const _Float16*)d_ws, hid, bih, bhh, out);
    } else {
        qgru_mfma_bf16x3<<<grid, dim3(256), 0, stream>>>(
            x, hid, wih, whh, bih, bhh, out);
    }
}